// Round 1
// baseline (487.225 us; speedup 1.0000x reference)
//
#include <hip/hip_runtime.h>
#include <hip/hip_bf16.h>

typedef __attribute__((ext_vector_type(8))) short bf16x8;
typedef __attribute__((ext_vector_type(4))) float f32x4;
typedef __attribute__((ext_vector_type(4))) float float4v;

static __device__ __forceinline__ unsigned short f2b(float f) {
  unsigned int u = __builtin_bit_cast(unsigned int, f);
  u += 0x7fffu + ((u >> 16) & 1u);
  return (unsigned short)(u >> 16);
}
static __device__ __forceinline__ float b2f(unsigned short s) {
  unsigned int u = ((unsigned int)s) << 16;
  return __builtin_bit_cast(float, u);
}
static __device__ __forceinline__ float siluf(float x) {
  return x / (1.f + expf(-x));
}

// ---------------------------------------------------------------------------
// Generic GEMM: C[M,N] = A[M,K] @ W[N,K]^T, bf16 inputs, fp32 accum (MFMA).
// 64x64 block tile, BK=32, 4 waves each computing a 32x32 quadrant (2x2 of
// 16x16x32 MFMA frags). Single-buffered LDS, reg-staged (correctness-first).
// MODE 0: v += bias[n];            write fp32 of[] and bf16 ob[]        (pre)
// MODE 1: n<512: silu(v*cw3+cb) -> ob (xi); n>=512: silu(v) -> ob2 (sz) (xz)
// MODE 2: v += of[]; write back of[] and bf16 ob[]                 (out_proj)
// MODE 3: plain fp32 store to of[]                                    (xdbl)
// AF32: A is fp32 in global; convert to bf16 during LDS staging.
// ---------------------------------------------------------------------------
template <int MODE, bool AF32>
__global__ __launch_bounds__(256) void gemm_bt(
    const void* __restrict__ Aptr, const unsigned short* __restrict__ W,
    int M, int N, int K,
    const float* __restrict__ p0, const float* __restrict__ p1,
    float* __restrict__ of, unsigned short* __restrict__ ob,
    unsigned short* __restrict__ ob2) {
  __shared__ __align__(16) unsigned short As[64 * 32];
  __shared__ __align__(16) unsigned short Ws[64 * 32];
  const int t = threadIdx.x;
  const int bm = blockIdx.x * 64;
  const int bn = blockIdx.y * 64;
  const int lane = t & 63;
  const int wave = t >> 6;
  const int wr = (wave >> 1) * 32;
  const int wc = (wave & 1) * 32;
  const int lr = lane & 15;
  const int lkb = (lane >> 4) * 8;

  const int srow = t >> 2;        // 0..63
  const int scol = (t & 3) * 8;   // 0,8,16,24

  f32x4 zero = {0.f, 0.f, 0.f, 0.f};
  f32x4 acc[2][2];
#pragma unroll
  for (int i = 0; i < 2; ++i)
#pragma unroll
    for (int j = 0; j < 2; ++j) acc[i][j] = zero;

  const unsigned short* Ab = (const unsigned short*)Aptr;
  const float* Af = (const float*)Aptr;
  const long aoff = (long)(bm + srow) * K;
  const long woff = (long)(bn + srow) * K;

  for (int k0 = 0; k0 < K; k0 += 32) {
    if constexpr (AF32) {
      const float4v* s4 = (const float4v*)(Af + aoff + k0 + scol);
      float4v a0 = s4[0], a1 = s4[1];
      bf16x8 v;
      v[0] = (short)f2b(a0[0]); v[1] = (short)f2b(a0[1]);
      v[2] = (short)f2b(a0[2]); v[3] = (short)f2b(a0[3]);
      v[4] = (short)f2b(a1[0]); v[5] = (short)f2b(a1[1]);
      v[6] = (short)f2b(a1[2]); v[7] = (short)f2b(a1[3]);
      *(bf16x8*)&As[srow * 32 + scol] = v;
    } else {
      *(bf16x8*)&As[srow * 32 + scol] = *(const bf16x8*)&Ab[aoff + k0 + scol];
    }
    *(bf16x8*)&Ws[srow * 32 + scol] = *(const bf16x8*)&W[woff + k0 + scol];
    __syncthreads();
    bf16x8 af0 = *(const bf16x8*)&As[(wr + lr) * 32 + lkb];
    bf16x8 af1 = *(const bf16x8*)&As[(wr + 16 + lr) * 32 + lkb];
    bf16x8 bg0 = *(const bf16x8*)&Ws[(wc + lr) * 32 + lkb];
    bf16x8 bg1 = *(const bf16x8*)&Ws[(wc + 16 + lr) * 32 + lkb];
    acc[0][0] = __builtin_amdgcn_mfma_f32_16x16x32_bf16(af0, bg0, acc[0][0], 0, 0, 0);
    acc[0][1] = __builtin_amdgcn_mfma_f32_16x16x32_bf16(af0, bg1, acc[0][1], 0, 0, 0);
    acc[1][0] = __builtin_amdgcn_mfma_f32_16x16x32_bf16(af1, bg0, acc[1][0], 0, 0, 0);
    acc[1][1] = __builtin_amdgcn_mfma_f32_16x16x32_bf16(af1, bg1, acc[1][1], 0, 0, 0);
    __syncthreads();
  }

  // C/D layout (verified m89): col = lane&15, row = (lane>>4)*4 + reg
  const int m0 = bm + wr + (lane >> 4) * 4;
  const int n0 = bn + wc + lr;
#pragma unroll
  for (int i = 0; i < 2; ++i)
#pragma unroll
    for (int j = 0; j < 2; ++j) {
      const int n = n0 + j * 16;
#pragma unroll
      for (int r = 0; r < 4; ++r) {
        const int m = m0 + i * 16 + r;
        float v = acc[i][j][r];
        if constexpr (MODE == 0) {
          v += p0[n];
          of[(long)m * N + n] = v;
          ob[(long)m * N + n] = f2b(v);
        } else if constexpr (MODE == 1) {
          if (n < 512) {
            float u = v * p0[n * 4 + 3] + p1[n];  // conv tap 3 + bias
            ob[(long)m * 512 + n] = f2b(siluf(u));
          } else {
            ob2[(long)m * 512 + (n - 512)] = f2b(siluf(v));
          }
        } else if constexpr (MODE == 2) {
          float nv = of[(long)m * N + n] + v;
          of[(long)m * N + n] = nv;
          ob[(long)m * N + n] = f2b(nv);
        } else {
          of[(long)m * N + n] = v;
        }
      }
    }
}

// fp32 -> bf16 weight conversion
__global__ void f2b_kernel(const float* __restrict__ s,
                           unsigned short* __restrict__ d, int n) {
  for (int i = blockIdx.x * 256 + threadIdx.x; i < n; i += gridDim.x * 256)
    d[i] = f2b(s[i]);
}

// x_proj (5,48,512) fp32 -> padded (5,64,512) bf16, rows 48..63 = 0
__global__ void pad_xw_kernel(const float* __restrict__ xw,
                              unsigned short* __restrict__ dst) {
  int i = blockIdx.x * 256 + threadIdx.x;
  if (i >= 5 * 64 * 512) return;
  int k = i & 511;
  int j = (i >> 9) & 63;
  int b = i >> 15;
  dst[i] = (j < 48) ? f2b(xw[((long)b * 48 + j) * 512 + k]) : (unsigned short)0;
}

// Per-row: dt = softplus(dtw @ xdbl[:16] + dtb); BC = dot(xdbl[16:32],xdbl[32:48])
// y = xi * (dt*BC + D) * silu(z)   (L=1 collapses the scan to this)
__global__ __launch_bounds__(256) void small_ops(
    const float* __restrict__ xdbl, const float* __restrict__ dtw,
    const float* __restrict__ dtb, const float* __restrict__ Dp,
    const unsigned short* __restrict__ xi, const unsigned short* __restrict__ sz,
    unsigned short* __restrict__ yb) {
  const int t = threadIdx.x;
  const int r0 = blockIdx.x * 32;
  for (int r = r0; r < r0 + 32; ++r) {
    const float* xr = xdbl + (long)r * 64;
    float dtr[16];
#pragma unroll
    for (int i = 0; i < 16; ++i) dtr[i] = xr[i];
    float BC = 0.f;
#pragma unroll
    for (int s = 0; s < 16; ++s) BC += xr[16 + s] * xr[32 + s];
#pragma unroll
    for (int dd = 0; dd < 2; ++dd) {
      const int d = t + dd * 256;
      float a = dtb[d];
#pragma unroll
      for (int i = 0; i < 16; ++i) a += dtw[d * 16 + i] * dtr[i];
      const float dtv = (a > 20.f) ? a : log1pf(expf(a));
      const float xiv = b2f(xi[(long)r * 512 + d]);
      const float szv = b2f(sz[(long)r * 512 + d]);
      const float y = xiv * (dtv * BC + Dp[d]) * szv;
      yb[(long)r * 512 + d] = f2b(y);
    }
  }
}

// LayerNorm(256) + classifier (8 outputs). One wave per row.
__global__ __launch_bounds__(256) void final_ln_cls(
    const float* __restrict__ h, const float* __restrict__ g,
    const float* __restrict__ be, const float* __restrict__ Wc,
    const float* __restrict__ bc, float* __restrict__ out) {
  const int wave = threadIdx.x >> 6, lane = threadIdx.x & 63;
  const int row = blockIdx.x * 4 + wave;
  const float4v* hr = (const float4v*)(h + (long)row * 256);
  float4v v = hr[lane];
  float s = v[0] + v[1] + v[2] + v[3];
#pragma unroll
  for (int o = 32; o; o >>= 1) s += __shfl_xor(s, o);
  const float mu = s * (1.f / 256.f);
  float d0 = v[0] - mu, d1 = v[1] - mu, d2 = v[2] - mu, d3 = v[3] - mu;
  float q = d0 * d0 + d1 * d1 + d2 * d2 + d3 * d3;
#pragma unroll
  for (int o = 32; o; o >>= 1) q += __shfl_xor(q, o);
  const float rs = rsqrtf(q * (1.f / 256.f) + 1e-5f);
  const float4v gv = ((const float4v*)g)[lane];
  const float4v bv = ((const float4v*)be)[lane];
  float hn[4];
  hn[0] = d0 * rs * gv[0] + bv[0];
  hn[1] = d1 * rs * gv[1] + bv[1];
  hn[2] = d2 * rs * gv[2] + bv[2];
  hn[3] = d3 * rs * gv[3] + bv[3];
  float lg[8];
#pragma unroll
  for (int o = 0; o < 8; ++o) {
    const float4v wv = ((const float4v*)(Wc + o * 256))[lane];
    float p = hn[0] * wv[0] + hn[1] * wv[1] + hn[2] * wv[2] + hn[3] * wv[3];
#pragma unroll
    for (int x = 32; x; x >>= 1) p += __shfl_xor(p, x);
    lg[o] = p;
  }
  if (lane == 0) {
#pragma unroll
    for (int o = 0; o < 8; ++o) out[(long)row * 8 + o] = lg[o] + bc[o];
  }
}

extern "C" void kernel_launch(void* const* d_in, const int* in_sizes, int n_in,
                              void* d_out, int out_size, void* d_ws,
                              size_t ws_size, hipStream_t stream) {
  const float* x      = (const float*)d_in[0];
  const float* W_pre  = (const float*)d_in[1];
  const float* b_pre  = (const float*)d_in[2];
  const float* in_w   = (const float*)d_in[3];
  const float* conv_w = (const float*)d_in[4];
  const float* conv_b = (const float*)d_in[5];
  const float* x_w    = (const float*)d_in[6];
  const float* dt_w   = (const float*)d_in[7];
  const float* dt_b   = (const float*)d_in[8];
  // d_in[9] = A_log: dead (scan starts from h0=0, L=1)
  const float* Dp     = (const float*)d_in[10];
  const float* out_w  = (const float*)d_in[11];
  const float* ln_g   = (const float*)d_in[12];
  const float* ln_b   = (const float*)d_in[13];
  const float* W_cls  = (const float*)d_in[14];
  const float* b_cls  = (const float*)d_in[15];
  float* out = (float*)d_out;

  char* w = (char*)d_ws;
  unsigned short* wpreb = (unsigned short*)w; w += 256 * 2048 * 2;
  unsigned short* inwb  = (unsigned short*)w; w += 5 * 1024 * 256 * 2;
  unsigned short* xwpb  = (unsigned short*)w; w += 5 * 64 * 512 * 2;
  unsigned short* owb   = (unsigned short*)w; w += 5 * 256 * 512 * 2;
  float*          h     = (float*)w;          w += 8192 * 256 * 4;
  unsigned short* hb    = (unsigned short*)w; w += 8192 * 256 * 2;
  unsigned short* xib   = (unsigned short*)w; w += 8192 * 512 * 2;
  unsigned short* szb   = (unsigned short*)w; w += 8192 * 512 * 2;
  unsigned short* yb    = (unsigned short*)w; w += 8192 * 512 * 2;
  float*          xdbl  = (float*)w;          w += 8192 * 64 * 4;

  // weight precasts (deterministic, every launch)
  f2b_kernel<<<1024, 256, 0, stream>>>(W_pre, wpreb, 256 * 2048);
  f2b_kernel<<<2048, 256, 0, stream>>>(in_w, inwb, 5 * 1024 * 256);
  f2b_kernel<<<1024, 256, 0, stream>>>(out_w, owb, 5 * 256 * 512);
  pad_xw_kernel<<<640, 256, 0, stream>>>(x_w, xwpb);

  // h = x @ W_pre^T + b_pre  (A fp32 staged->bf16)
  gemm_bt<0, true><<<dim3(128, 4), 256, 0, stream>>>(
      (const void*)x, wpreb, 8192, 256, 2048, b_pre, nullptr, h, hb, nullptr);

  for (int blk = 0; blk < 5; ++blk) {
    // xz = h @ in_w^T ; xi = silu(xz[:512]*cw3+cb) ; sz = silu(xz[512:])
    gemm_bt<1, false><<<dim3(128, 16), 256, 0, stream>>>(
        (const void*)hb, inwb + blk * 1024 * 256, 8192, 1024, 256,
        conv_w + blk * 512 * 4, conv_b + blk * 512, nullptr, xib, szb);
    // xdbl = xi @ x_w^T (N padded 48->64)
    gemm_bt<3, false><<<dim3(128, 1), 256, 0, stream>>>(
        (const void*)xib, xwpb + blk * 64 * 512, 8192, 64, 512,
        nullptr, nullptr, xdbl, nullptr, nullptr);
    // dt/BC/y elementwise
    small_ops<<<256, 256, 0, stream>>>(
        xdbl, dt_w + blk * 512 * 16, dt_b + blk * 512, Dp + blk * 512,
        xib, szb, yb);
    // h += y @ out_w^T
    gemm_bt<2, false><<<dim3(128, 4), 256, 0, stream>>>(
        (const void*)yb, owb + blk * 256 * 512, 8192, 256, 512,
        nullptr, nullptr, h, hb, nullptr);
  }

  final_ln_cls<<<2048, 256, 0, stream>>>(h, ln_g, ln_b, W_cls, b_cls, out);
}